// Round 8
// baseline (647.440 us; speedup 1.0000x reference)
//
#include <hip/hip_runtime.h>
#include <math.h>

#define BB 4
#define SS 4096
#define DD 1024
#define TPp 16
#define TEe 64
#define DKk 128

typedef __attribute__((ext_vector_type(8))) short short8;
typedef __attribute__((ext_vector_type(4))) float floatx4;
typedef __attribute__((ext_vector_type(16))) float floatx16;

#define BSTRIDE 524288   // 4096*128 shorts per batch for frag-layout arrays
#define WFRAG 131072     // shorts per weight matrix in B-frag layout (1024x128)
#define XTILE 32768      // shorts per 32-row x tile in A-frag layout (32x1024)

// bf16 helpers (RNE, branchless)
static __device__ inline short f2bf(float f) {
  union { float f; unsigned u; } v; v.f = f;
  unsigned r = v.u + 0x7fff + ((v.u >> 16) & 1);
  return (short)(r >> 16);
}
static __device__ inline float bf2f(short s) {
  union { unsigned u; float f; } v; v.u = ((unsigned)(unsigned short)s) << 16;
  return v.f;
}

// ---------------- Kernel A1: E = tp@Wt + bt ; T_scaled ; bqt = bq@T ----------------
__global__ __launch_bounds__(256) void temb_kernel(const float* __restrict__ tp,
                                                   const float* __restrict__ Wt,
                                                   const float* __restrict__ bt,
                                                   const float* __restrict__ bq,
                                                   float* __restrict__ Tws,
                                                   float* __restrict__ bqtws) {
  __shared__ float sE[TPp * DKk];
  __shared__ float sB[TPp];
  __shared__ float red[256];
  const int p = blockIdx.x, b = blockIdx.y;
  const int tid = threadIdx.x;
  float lsq = 0.f;
  for (int l = 0; l < 8; ++l) {
    int idx = tid + 256 * l;
    int i = idx >> 7, j = idx & 127;
    float a = bt[j];
    for (int c = 0; c < TEe; ++c)
      a += tp[((size_t)b * TPp + i) * TEe + c] * Wt[c * DKk + j];
    sE[idx] = a;
    lsq += a * a;
  }
  red[tid] = lsq;
  __syncthreads();
  for (int s2 = 128; s2 > 0; s2 >>= 1) {
    if (tid < s2) red[tid] += red[tid + s2];
    __syncthreads();
  }
  const float total = red[0];
  const float scale = (float)SS / (sqrtf((float)SS * total) + 1e-8f);
  if (tid < TPp) {
    float a = 0.f;
    for (int d2 = 0; d2 < DKk; ++d2) a += bq[d2] * sE[tid * DKk + d2];
    sB[tid] = a;
  }
  __syncthreads();
  for (int l = 0; l < 8; ++l) {
    int idx = p * 2048 + tid + 256 * l;
    int d2 = idx >> 7, e = idx & 127;
    float a = 0.f;
    #pragma unroll
    for (int t = 0; t < TPp; ++t) a += sE[t * DKk + d2] * sE[t * DKk + e];
    Tws[(size_t)b * DKk * DKk + idx] = scale * a;
  }
  if (p == 0 && tid < DKk) {
    float a = 0.f;
    #pragma unroll
    for (int t = 0; t < TPp; ++t) a += sB[t] * sE[t * DKk + tid];
    bqtws[b * DKk + tid] = scale * a;
  }
}

// ---------------- Kernel A2: Wqp[b] = Wq @ T[b], written directly as hi/lo B-frags --
__global__ __launch_bounds__(128) void wqp_kernel(const float* __restrict__ Wq,
                                                  const float* __restrict__ Tws,
                                                  short* __restrict__ WqphF,
                                                  short* __restrict__ WqplF) {
  __shared__ float sW[DKk];
  const int m = blockIdx.x, b = blockIdx.y;   // m = k-index of Wqp
  const int e = threadIdx.x;                  // n-index
  sW[e] = Wq[(size_t)m * DKk + e];
  __syncthreads();
  const float* Tb = Tws + (size_t)b * DKk * DKk;
  float a = 0.f;
  #pragma unroll 8
  for (int d2 = 0; d2 < DKk; ++d2) a += sW[d2] * Tb[d2 * DKk + e];
  const size_t off = (size_t)b * WFRAG +
      (size_t)((e >> 5) * 64 + (m >> 4)) * 512 + (32 * ((m >> 3) & 1) + (e & 31)) * 8 +
      (m & 7);
  short hh = f2bf(a);
  WqphF[off] = hh;
  WqplF[off] = f2bf(a - bf2f(hh));
}

// ---------------- Kernel A3: Wk/Wv -> hi/lo B-frags ----------------
__global__ __launch_bounds__(256) void wcast_kernel(const float* __restrict__ Wk,
                                                    const float* __restrict__ Wv,
                                                    short* __restrict__ WkhF,
                                                    short* __restrict__ WklF,
                                                    short* __restrict__ WvhF,
                                                    short* __restrict__ WvlF) {
  const float* W = blockIdx.y ? Wv : Wk;
  short* H = blockIdx.y ? WvhF : WkhF;
  short* L = blockIdx.y ? WvlF : WklF;
  const int ks = blockIdx.x;                     // 0..63
  const int wave = threadIdx.x >> 6, lane = threadIdx.x & 63;
  const int n = wave * 32 + (lane & 31);
  const int k0 = ks * 16 + (lane >> 5) * 8;
  short8 h, l;
  #pragma unroll
  for (int j = 0; j < 8; ++j) {
    float v = W[(size_t)(k0 + j) * DKk + n];
    short hh = f2bf(v);
    h[j] = hh;
    l[j] = f2bf(v - bf2f(hh));
  }
  const size_t off = ((size_t)wave * 64 + ks) * 512 + lane * 8;
  *(short8*)&H[off] = h;
  *(short8*)&L[off] = l;
}

// ---------------- Kernel A4: x -> split-bf16 A-frags ----------------
__global__ __launch_bounds__(256) void xcast_kernel(const float* __restrict__ x,
                                                    short* __restrict__ XAh,
                                                    short* __restrict__ XAl) {
  const int tileG = blockIdx.x;           // 0..511
  const int rowbase = tileG * 32;
  const int tid = threadIdx.x;
  const int t = tid & 31, khalf = (tid >> 5) & 1, w = tid >> 6;
  const size_t abase = (size_t)tileG * XTILE + (size_t)(tid & 63) * 8;
  const float* xr = x + (size_t)(rowbase + t) * DD + khalf * 8;
  #pragma unroll
  for (int it = 0; it < 16; ++it) {
    const int ks = it * 4 + w;
    float4 u0 = *(const float4*)(xr + ks * 16);
    float4 u1 = *(const float4*)(xr + ks * 16 + 4);
    const float v[8] = {u0.x, u0.y, u0.z, u0.w, u1.x, u1.y, u1.z, u1.w};
    short8 h, l;
    #pragma unroll
    for (int j = 0; j < 8; ++j) {
      short hh = f2bf(v[j]);
      h[j] = hh;
      l[j] = f2bf(v[j] - bf2f(hh));
    }
    *(short8*)&XAh[abase + (size_t)ks * 512] = h;
    *(short8*)&XAl[abase + (size_t)ks * 512] = l;
  }
}

// ---------------- Kernel B: streaming MFMA projection, all 3 regions per block ------
// A-frags read once, 3 independent acc chains (QT/K/V). Grid 512.
__global__ __launch_bounds__(256, 2) void proj_kernel(const short* __restrict__ XAh,
                                                      const short* __restrict__ XAl,
                                                      const short* __restrict__ WqphF,
                                                      const short* __restrict__ WqplF,
                                                      const short* __restrict__ WkhF,
                                                      const short* __restrict__ WklF,
                                                      const short* __restrict__ WvhF,
                                                      const short* __restrict__ WvlF,
                                                      const float* __restrict__ bqt,
                                                      const float* __restrict__ bk,
                                                      const float* __restrict__ bv,
                                                      short* __restrict__ QTh,
                                                      short* __restrict__ QTl,
                                                      short* __restrict__ Kh,
                                                      short* __restrict__ Kl,
                                                      short* __restrict__ VT) {
  const int tileG = blockIdx.x;             // 0..511
  const int b = tileG >> 7, tileL = tileG & 127;
  const int tid = threadIdx.x, wave = tid >> 6, lane = tid & 63;
  const int l31 = lane & 31, half = lane >> 5;
  const size_t woff = (size_t)wave * 32768 + (size_t)lane * 8;
  const short* BQh = WqphF + (size_t)b * WFRAG + woff;
  const short* BQl = WqplF + (size_t)b * WFRAG + woff;
  const short* BKh = WkhF + woff;
  const short* BKl = WklF + woff;
  const short* BVh = WvhF + woff;
  const short* BVl = WvlF + woff;
  const short* AH = XAh + (size_t)tileG * XTILE + (size_t)lane * 8;
  const short* AL = XAl + (size_t)tileG * XTILE + (size_t)lane * 8;
  floatx16 acc0, acc1, acc2;
  #pragma unroll
  for (int r = 0; r < 16; ++r) { acc0[r] = 0.f; acc1[r] = 0.f; acc2[r] = 0.f; }
  for (int ks = 0; ks < 64; ++ks) {
    const size_t o = (size_t)ks * 512;
    short8 ah = *(const short8*)(AH + o);
    short8 al = *(const short8*)(AL + o);
    short8 bh0 = *(const short8*)(BQh + o);
    short8 bl0 = *(const short8*)(BQl + o);
    short8 bh1 = *(const short8*)(BKh + o);
    short8 bl1 = *(const short8*)(BKl + o);
    short8 bh2 = *(const short8*)(BVh + o);
    short8 bl2 = *(const short8*)(BVl + o);
    acc0 = __builtin_amdgcn_mfma_f32_32x32x16_bf16(al, bh0, acc0, 0, 0, 0);
    acc1 = __builtin_amdgcn_mfma_f32_32x32x16_bf16(al, bh1, acc1, 0, 0, 0);
    acc2 = __builtin_amdgcn_mfma_f32_32x32x16_bf16(al, bh2, acc2, 0, 0, 0);
    acc0 = __builtin_amdgcn_mfma_f32_32x32x16_bf16(ah, bl0, acc0, 0, 0, 0);
    acc1 = __builtin_amdgcn_mfma_f32_32x32x16_bf16(ah, bl1, acc1, 0, 0, 0);
    acc2 = __builtin_amdgcn_mfma_f32_32x32x16_bf16(ah, bl2, acc2, 0, 0, 0);
    acc0 = __builtin_amdgcn_mfma_f32_32x32x16_bf16(ah, bh0, acc0, 0, 0, 0);
    acc1 = __builtin_amdgcn_mfma_f32_32x32x16_bf16(ah, bh1, acc1, 0, 0, 0);
    acc2 = __builtin_amdgcn_mfma_f32_32x32x16_bf16(ah, bh2, acc2, 0, 0, 0);
  }
  // Epilogue. C/D: col(n) = wave*32 + l31, row(t) = (reg&3)+8*(reg>>2)+4*half.
  const int f = wave * 32 + l31;
  const int fks = f >> 4, fh = (f >> 3) & 1, fj = f & 7;
  const size_t qkbase =
      (size_t)b * BSTRIDE + (size_t)tileL * 4096 + (size_t)fks * 512 + fj;
  const float biasq = bqt[b * DKk + f];
  const float biask = bk[f];
  #pragma unroll
  for (int reg = 0; reg < 16; ++reg) {
    const int t = (reg & 3) + 8 * (reg >> 2) + 4 * half;
    const size_t off = qkbase + (size_t)(fh * 32 + t) * 8;
    float v = acc0[reg] + biasq;
    short hh = f2bf(v);
    QTh[off] = hh;
    QTl[off] = f2bf(v - bf2f(hh));
    v = acc1[reg] + biask;
    hh = f2bf(v);
    Kh[off] = hh;
    Kl[off] = f2bf(v - bf2f(hh));
  }
  // V -> 32x32x16 B-operand layout over [t][d]:
  const float biasv = bv[f];
  #pragma unroll
  for (int g = 0; g < 4; ++g) {
    short4 s4;
    s4.x = f2bf(acc2[4 * g + 0] + biasv);
    s4.y = f2bf(acc2[4 * g + 1] + biasv);
    s4.z = f2bf(acc2[4 * g + 2] + biasv);
    s4.w = f2bf(acc2[4 * g + 3] + biasv);
    const size_t off = (size_t)b * BSTRIDE +
        (size_t)(wave * 256 + tileL * 2 + (g >> 1)) * 512 +
        (size_t)((g & 1) * 32 + l31) * 8 + 4 * half;
    *(short4*)&VT[off] = s4;
  }
}

// ---------------- Kernel C1: partial m/l. 128 q-rows/block (4 waves x 1 tile each),
// waves share the same ct stream (K served from L1). ct 4-way split across blocks.
__global__ __launch_bounds__(256, 2) void ml_kernel(const short* __restrict__ QTh,
                                                    const short* __restrict__ QTl,
                                                    const short* __restrict__ Kh,
                                                    const short* __restrict__ Kl,
                                                    float* __restrict__ mlP) {
  const int id = blockIdx.x;                 // 512
  const int s = id & 3;                      // ct split
  const int b = (id >> 2) & 3;
  const int rg = id >> 4;                    // 0..31
  const int tid = threadIdx.x;
  const int wave = tid >> 6, lane = tid & 63;
  const int l31 = lane & 31;
  const int qtile = rg * 4 + wave;           // 0..127
  const float sc = 0.088388347648318447f;
  const size_t qbase = (size_t)b * BSTRIDE + (size_t)qtile * 4096 + lane * 8;
  short8 qh[8], ql[8];
  #pragma unroll
  for (int ks = 0; ks < 8; ++ks) {
    qh[ks] = *(const short8*)(QTh + qbase + ks * 512);
    ql[ks] = *(const short8*)(QTl + qbase + ks * 512);
  }
  float m = -INFINITY, l = 0.f;
  for (int i = 0; i < 32; ++i) {
    const int ct = s * 32 + i;
    const size_t kbase = (size_t)b * BSTRIDE + (size_t)ct * 4096 + lane * 8;
    floatx16 accA, accB;
    #pragma unroll
    for (int r = 0; r < 16; ++r) { accA[r] = 0.f; accB[r] = 0.f; }
    #pragma unroll
    for (int ks = 0; ks < 4; ++ks) {
      short8 kh0 = *(const short8*)(Kh + kbase + ks * 512);
      short8 kl0 = *(const short8*)(Kl + kbase + ks * 512);
      short8 kh1 = *(const short8*)(Kh + kbase + (ks + 4) * 512);
      short8 kl1 = *(const short8*)(Kl + kbase + (ks + 4) * 512);
      accA = __builtin_amdgcn_mfma_f32_32x32x16_bf16(kh0, qh[ks], accA, 0, 0, 0);
      accB = __builtin_amdgcn_mfma_f32_32x32x16_bf16(kh1, qh[ks + 4], accB, 0, 0, 0);
      accA = __builtin_amdgcn_mfma_f32_32x32x16_bf16(kh0, ql[ks], accA, 0, 0, 0);
      accB = __builtin_amdgcn_mfma_f32_32x32x16_bf16(kh1, ql[ks + 4], accB, 0, 0, 0);
      accA = __builtin_amdgcn_mfma_f32_32x32x16_bf16(kl0, qh[ks], accA, 0, 0, 0);
      accB = __builtin_amdgcn_mfma_f32_32x32x16_bf16(kl1, qh[ks + 4], accB, 0, 0, 0);
    }
    float sv[16];
    float tmax = -INFINITY;
    #pragma unroll
    for (int r = 0; r < 16; ++r) {
      sv[r] = (accA[r] + accB[r]) * sc;
      tmax = fmaxf(tmax, sv[r]);
    }
    const float mn = fmaxf(m, tmax);
    float ps = 0.f;
    #pragma unroll
    for (int r = 0; r < 16; ++r) ps += __expf(sv[r] - mn);
    l = l * __expf(m - mn) + ps;
    m = mn;
  }
  {
    const float mo = __shfl_xor(m, 32, 64);
    const float lo = __shfl_xor(l, 32, 64);
    const float mn = fmaxf(m, mo);
    l = l * __expf(m - mn) + lo * __expf(mo - mn);
    m = mn;
  }
  if (lane < 32) {
    const int q = b * SS + qtile * 32 + l31;
    mlP[(s * 2 + 0) * (BB * SS) + q] = m;
    mlP[(s * 2 + 1) * (BB * SS) + q] = l;
  }
}

// ---------------- Kernel C1b: combine 4 ct-split partials -> mrow, linv -------------
__global__ __launch_bounds__(256) void mlred_kernel(const float* __restrict__ mlP,
                                                    float* __restrict__ mrow,
                                                    float* __restrict__ linv) {
  const int q = blockIdx.x * 256 + threadIdx.x;   // 0..16383
  float m = mlP[q], l = mlP[BB * SS + q];
  #pragma unroll
  for (int s = 1; s < 4; ++s) {
    const float mo = mlP[(s * 2 + 0) * (BB * SS) + q];
    const float lo = mlP[(s * 2 + 1) * (BB * SS) + q];
    const float mn = fmaxf(m, mo);
    l = l * __expf(m - mn) + lo * __expf(mo - mn);
    m = mn;
  }
  mrow[q] = m;
  linv[q] = 1.0f / l;
}

// ---------------- Kernel C2: recompute scores (identical per-tile chains), write p,
// partial P@V into outP. Same block decomposition as ml_kernel. ----------------------
__global__ __launch_bounds__(256, 2) void pv_kernel(const short* __restrict__ QTh,
                                                    const short* __restrict__ QTl,
                                                    const short* __restrict__ Kh,
                                                    const short* __restrict__ Kl,
                                                    const short* __restrict__ VT,
                                                    float* __restrict__ attn,
                                                    const float* __restrict__ mrow,
                                                    const float* __restrict__ linv,
                                                    float* __restrict__ outP) {
  const int id = blockIdx.x;                 // 512
  const int s = id & 3;
  const int b = (id >> 2) & 3;
  const int rg = id >> 4;
  const int tid = threadIdx.x;
  const int wave = tid >> 6, lane = tid & 63;
  const int l31 = lane & 31, half = lane >> 5;
  const int qtile = rg * 4 + wave;
  const float sc = 0.088388347648318447f;
  const size_t qbase = (size_t)b * BSTRIDE + (size_t)qtile * 4096 + lane * 8;
  short8 qh[8], ql[8];
  #pragma unroll
  for (int ks = 0; ks < 8; ++ks) {
    qh[ks] = *(const short8*)(QTh + qbase + ks * 512);
    ql[ks] = *(const short8*)(QTl + qbase + ks * 512);
  }
  const float m_i = mrow[b * SS + qtile * 32 + l31];
  const float li = linv[b * SS + qtile * 32 + l31];
  float* arow = attn + (size_t)b * SS * SS + (size_t)(qtile * 32 + l31) * SS + 4 * half;
  const short* vtb = VT + (size_t)b * BSTRIDE + lane * 8;
  floatx16 pacc[4];
  #pragma unroll
  for (int dt = 0; dt < 4; ++dt)
    #pragma unroll
    for (int r = 0; r < 16; ++r) pacc[dt][r] = 0.f;
  for (int i = 0; i < 32; ++i) {
    const int ct = s * 32 + i;
    const size_t kbase = (size_t)b * BSTRIDE + (size_t)ct * 4096 + lane * 8;
    floatx16 accA, accB;
    #pragma unroll
    for (int r = 0; r < 16; ++r) { accA[r] = 0.f; accB[r] = 0.f; }
    #pragma unroll
    for (int ks = 0; ks < 4; ++ks) {
      short8 kh0 = *(const short8*)(Kh + kbase + ks * 512);
      short8 kl0 = *(const short8*)(Kl + kbase + ks * 512);
      short8 kh1 = *(const short8*)(Kh + kbase + (ks + 4) * 512);
      short8 kl1 = *(const short8*)(Kl + kbase + (ks + 4) * 512);
      accA = __builtin_amdgcn_mfma_f32_32x32x16_bf16(kh0, qh[ks], accA, 0, 0, 0);
      accB = __builtin_amdgcn_mfma_f32_32x32x16_bf16(kh1, qh[ks + 4], accB, 0, 0, 0);
      accA = __builtin_amdgcn_mfma_f32_32x32x16_bf16(kh0, ql[ks], accA, 0, 0, 0);
      accB = __builtin_amdgcn_mfma_f32_32x32x16_bf16(kh1, ql[ks + 4], accB, 0, 0, 0);
      accA = __builtin_amdgcn_mfma_f32_32x32x16_bf16(kl0, qh[ks], accA, 0, 0, 0);
      accB = __builtin_amdgcn_mfma_f32_32x32x16_bf16(kl1, qh[ks + 4], accB, 0, 0, 0);
    }
    float p[16];
    #pragma unroll
    for (int r = 0; r < 16; ++r)
      p[r] = __expf((accA[r] + accB[r]) * sc - m_i) * li;
    #pragma unroll
    for (int g = 0; g < 4; ++g) {
      floatx4 o = {p[4 * g], p[4 * g + 1], p[4 * g + 2], p[4 * g + 3]};
      *(floatx4*)(arow + ct * 32 + 8 * g) = o;
    }
    // C->A frags (k = t): af0 covers t'=0..15, af1 covers t'=16..31
    short8 af0, af1;
    #pragma unroll
    for (int rr = 0; rr < 4; ++rr) {
      const float shl = __shfl_xor(p[rr], 32, 64);
      const float shh = __shfl_xor(p[rr + 4], 32, 64);
      af0[rr] = f2bf(half ? shh : p[rr]);
      af0[rr + 4] = f2bf(half ? p[rr + 4] : shl);
      const float shl2 = __shfl_xor(p[rr + 8], 32, 64);
      const float shh2 = __shfl_xor(p[rr + 12], 32, 64);
      af1[rr] = f2bf(half ? shh2 : p[rr + 8]);
      af1[rr + 4] = f2bf(half ? p[rr + 12] : shl2);
    }
    #pragma unroll
    for (int dt = 0; dt < 4; ++dt) {
      short8 v0 = *(const short8*)(vtb + (size_t)(dt * 256 + ct * 2) * 512);
      pacc[dt] = __builtin_amdgcn_mfma_f32_32x32x16_bf16(af0, v0, pacc[dt], 0, 0, 0);
      short8 v1 = *(const short8*)(vtb + (size_t)(dt * 256 + ct * 2 + 1) * 512);
      pacc[dt] = __builtin_amdgcn_mfma_f32_32x32x16_bf16(af1, v1, pacc[dt], 0, 0, 0);
    }
  }
  // write partial out: D[m=q][n=d]; lane col d = dt*32 + l31, rows q from regs
  float* op = outP + (size_t)s * (BB * SS * DKk);
  #pragma unroll
  for (int dt = 0; dt < 4; ++dt)
    #pragma unroll
    for (int r = 0; r < 16; ++r) {
      const int qloc = (r & 3) + 8 * (r >> 2) + 4 * half;
      op[((size_t)b * SS + qtile * 32 + qloc) * DKk + dt * 32 + l31] = pacc[dt][r];
    }
}

// ---------------- Kernel C2b: out = sum of 4 ct-split partials ----------------------
__global__ __launch_bounds__(256) void outred_kernel(const float* __restrict__ outP,
                                                     float* __restrict__ outp) {
  const size_t idx = ((size_t)blockIdx.x * 256 + threadIdx.x) * 4;
  const size_t N = (size_t)BB * SS * DKk;
  floatx4 a0 = *(const floatx4*)(outP + idx);
  floatx4 a1 = *(const floatx4*)(outP + N + idx);
  floatx4 a2 = *(const floatx4*)(outP + 2 * N + idx);
  floatx4 a3 = *(const floatx4*)(outP + 3 * N + idx);
  floatx4 r = a0 + a1 + a2 + a3;
  *(floatx4*)(outp + idx) = r;
}

extern "C" void kernel_launch(void* const* d_in, const int* in_sizes, int n_in,
                              void* d_out, int out_size, void* d_ws, size_t ws_size,
                              hipStream_t stream) {
  const float* x  = (const float*)d_in[0];
  const float* tp = (const float*)d_in[1];
  const float* Wq = (const float*)d_in[2];
  const float* bq = (const float*)d_in[3];
  const float* Wk = (const float*)d_in[4];
  const float* bk = (const float*)d_in[5];
  const float* Wv = (const float*)d_in[6];
  const float* bv = (const float*)d_in[7];
  const float* Wt = (const float*)d_in[8];
  const float* bt = (const float*)d_in[9];
  float* out  = (float*)d_out;
  float* attn = out + (size_t)BB * SS * DKk;
  float* ws = (float*)d_ws;
  float* Tws   = ws;                          // 65536
  float* bqt   = ws + 65536;                  // 512
  short* WqphF = (short*)(ws + 66048);        // 524288 shorts (4 batches)
  short* WqplF = (short*)(ws + 328192);
  short* WkhF  = (short*)(ws + 590336);       // 131072 shorts each
  short* WklF  = (short*)(ws + 655872);
  short* WvhF  = (short*)(ws + 721408);
  short* WvlF  = (short*)(ws + 786944);
  short* XAh   = (short*)(ws + 852480);       // 16777216 shorts
  short* XAl   = (short*)(ws + 9241088);
  short* QTh   = (short*)(ws + 17629696);     // 2097152 shorts each
  short* QTl   = (short*)(ws + 18678272);
  short* Kh    = (short*)(ws + 19726848);
  short* Kl    = (short*)(ws + 20775424);
  short* VT    = (short*)(ws + 21824000);
  float* mrow  = ws + 22872576;               // 16384
  float* lin   = ws + 22888960;               // 16384
  float* mlP   = ws + 22905344;               // 4*2*16384 = 131072
  float* outP  = ws + 23036416;               // 4*2097152 = 8388608
                                              // end 31425024 fl = 125.7 MiB

  temb_kernel<<<dim3(8, 4), 256, 0, stream>>>(tp, Wt, bt, bq, Tws, bqt);
  wqp_kernel<<<dim3(1024, 4), 128, 0, stream>>>(Wq, Tws, WqphF, WqplF);
  wcast_kernel<<<dim3(64, 2), 256, 0, stream>>>(Wk, Wv, WkhF, WklF, WvhF, WvlF);
  xcast_kernel<<<512, 256, 0, stream>>>(x, XAh, XAl);
  proj_kernel<<<512, 256, 0, stream>>>(XAh, XAl, WqphF, WqplF, WkhF, WklF,
                                       WvhF, WvlF, bqt, bk, bv,
                                       QTh, QTl, Kh, Kl, VT);
  ml_kernel<<<512, 256, 0, stream>>>(QTh, QTl, Kh, Kl, mlP);
  mlred_kernel<<<64, 256, 0, stream>>>(mlP, mrow, lin);
  pv_kernel<<<512, 256, 0, stream>>>(QTh, QTl, Kh, Kl, VT, attn, mrow, lin, outP);
  outred_kernel<<<2048, 256, 0, stream>>>(outP, out);
}

// Round 9
// 589.176 us; speedup vs baseline: 1.0989x; 1.0989x over previous
//
#include <hip/hip_runtime.h>
#include <math.h>

#define BB 4
#define SS 4096
#define DD 1024
#define TPp 16
#define TEe 64
#define DKk 128

typedef __attribute__((ext_vector_type(8))) short short8;
typedef __attribute__((ext_vector_type(4))) float floatx4;
typedef __attribute__((ext_vector_type(16))) float floatx16;

#define BSTRIDE 524288   // 4096*128 shorts per batch for frag-layout arrays
#define WFRAG 131072     // shorts per weight matrix in B-frag layout (1024x128)
#define XTILE 32768      // shorts per 32-row x tile in A-frag layout (32x1024)

// bf16 helpers (RNE, branchless)
static __device__ inline short f2bf(float f) {
  union { float f; unsigned u; } v; v.f = f;
  unsigned r = v.u + 0x7fff + ((v.u >> 16) & 1);
  return (short)(r >> 16);
}
static __device__ inline float bf2f(short s) {
  union { unsigned u; float f; } v; v.u = ((unsigned)(unsigned short)s) << 16;
  return v.f;
}

// ---------------- Kernel A1: E = tp@Wt + bt ; T_scaled ; bqt = bq@T ----------------
__global__ __launch_bounds__(256) void temb_kernel(const float* __restrict__ tp,
                                                   const float* __restrict__ Wt,
                                                   const float* __restrict__ bt,
                                                   const float* __restrict__ bq,
                                                   float* __restrict__ Tws,
                                                   float* __restrict__ bqtws) {
  __shared__ float sE[TPp * DKk];
  __shared__ float sB[TPp];
  __shared__ float red[256];
  const int p = blockIdx.x, b = blockIdx.y;
  const int tid = threadIdx.x;
  float lsq = 0.f;
  for (int l = 0; l < 8; ++l) {
    int idx = tid + 256 * l;
    int i = idx >> 7, j = idx & 127;
    float a = bt[j];
    for (int c = 0; c < TEe; ++c)
      a += tp[((size_t)b * TPp + i) * TEe + c] * Wt[c * DKk + j];
    sE[idx] = a;
    lsq += a * a;
  }
  red[tid] = lsq;
  __syncthreads();
  for (int s2 = 128; s2 > 0; s2 >>= 1) {
    if (tid < s2) red[tid] += red[tid + s2];
    __syncthreads();
  }
  const float total = red[0];
  const float scale = (float)SS / (sqrtf((float)SS * total) + 1e-8f);
  if (tid < TPp) {
    float a = 0.f;
    for (int d2 = 0; d2 < DKk; ++d2) a += bq[d2] * sE[tid * DKk + d2];
    sB[tid] = a;
  }
  __syncthreads();
  for (int l = 0; l < 8; ++l) {
    int idx = p * 2048 + tid + 256 * l;
    int d2 = idx >> 7, e = idx & 127;
    float a = 0.f;
    #pragma unroll
    for (int t = 0; t < TPp; ++t) a += sE[t * DKk + d2] * sE[t * DKk + e];
    Tws[(size_t)b * DKk * DKk + idx] = scale * a;
  }
  if (p == 0 && tid < DKk) {
    float a = 0.f;
    #pragma unroll
    for (int t = 0; t < TPp; ++t) a += sB[t] * sE[t * DKk + tid];
    bqtws[b * DKk + tid] = scale * a;
  }
}

// ---------------- Kernel A2: Wqp[b] = Wq @ T[b], written directly as hi/lo B-frags --
__global__ __launch_bounds__(128) void wqp_kernel(const float* __restrict__ Wq,
                                                  const float* __restrict__ Tws,
                                                  short* __restrict__ WqphF,
                                                  short* __restrict__ WqplF) {
  __shared__ float sW[DKk];
  const int m = blockIdx.x, b = blockIdx.y;   // m = k-index of Wqp
  const int e = threadIdx.x;                  // n-index
  sW[e] = Wq[(size_t)m * DKk + e];
  __syncthreads();
  const float* Tb = Tws + (size_t)b * DKk * DKk;
  float a = 0.f;
  #pragma unroll 8
  for (int d2 = 0; d2 < DKk; ++d2) a += sW[d2] * Tb[d2 * DKk + e];
  const size_t off = (size_t)b * WFRAG +
      (size_t)((e >> 5) * 64 + (m >> 4)) * 512 + (32 * ((m >> 3) & 1) + (e & 31)) * 8 +
      (m & 7);
  short hh = f2bf(a);
  WqphF[off] = hh;
  WqplF[off] = f2bf(a - bf2f(hh));
}

// ---------------- Kernel A3: Wk/Wv -> hi/lo B-frags ----------------
__global__ __launch_bounds__(256) void wcast_kernel(const float* __restrict__ Wk,
                                                    const float* __restrict__ Wv,
                                                    short* __restrict__ WkhF,
                                                    short* __restrict__ WklF,
                                                    short* __restrict__ WvhF,
                                                    short* __restrict__ WvlF) {
  const float* W = blockIdx.y ? Wv : Wk;
  short* H = blockIdx.y ? WvhF : WkhF;
  short* L = blockIdx.y ? WvlF : WklF;
  const int ks = blockIdx.x;                     // 0..63
  const int wave = threadIdx.x >> 6, lane = threadIdx.x & 63;
  const int n = wave * 32 + (lane & 31);
  const int k0 = ks * 16 + (lane >> 5) * 8;
  short8 h, l;
  #pragma unroll
  for (int j = 0; j < 8; ++j) {
    float v = W[(size_t)(k0 + j) * DKk + n];
    short hh = f2bf(v);
    h[j] = hh;
    l[j] = f2bf(v - bf2f(hh));
  }
  const size_t off = ((size_t)wave * 64 + ks) * 512 + lane * 8;
  *(short8*)&H[off] = h;
  *(short8*)&L[off] = l;
}

// ---------------- Kernel A4: x -> split-bf16 A-frags ----------------
__global__ __launch_bounds__(256) void xcast_kernel(const float* __restrict__ x,
                                                    short* __restrict__ XAh,
                                                    short* __restrict__ XAl) {
  const int tileG = blockIdx.x;           // 0..511
  const int rowbase = tileG * 32;
  const int tid = threadIdx.x;
  const int t = tid & 31, khalf = (tid >> 5) & 1, w = tid >> 6;
  const size_t abase = (size_t)tileG * XTILE + (size_t)(tid & 63) * 8;
  const float* xr = x + (size_t)(rowbase + t) * DD + khalf * 8;
  #pragma unroll
  for (int it = 0; it < 16; ++it) {
    const int ks = it * 4 + w;
    float4 u0 = *(const float4*)(xr + ks * 16);
    float4 u1 = *(const float4*)(xr + ks * 16 + 4);
    const float v[8] = {u0.x, u0.y, u0.z, u0.w, u1.x, u1.y, u1.z, u1.w};
    short8 h, l;
    #pragma unroll
    for (int j = 0; j < 8; ++j) {
      short hh = f2bf(v[j]);
      h[j] = hh;
      l[j] = f2bf(v[j] - bf2f(hh));
    }
    *(short8*)&XAh[abase + (size_t)ks * 512] = h;
    *(short8*)&XAl[abase + (size_t)ks * 512] = l;
  }
}

// ---------------- Kernel B: streaming MFMA projection, one region per block --------
// Grid 1536: region = id>>9 (0:QT 1:K 2:V), tileG = id&511. No LDS, dual acc chains.
__global__ __launch_bounds__(256, 4) void proj_kernel(const short* __restrict__ XAh,
                                                      const short* __restrict__ XAl,
                                                      const short* __restrict__ WqphF,
                                                      const short* __restrict__ WqplF,
                                                      const short* __restrict__ WkhF,
                                                      const short* __restrict__ WklF,
                                                      const short* __restrict__ WvhF,
                                                      const short* __restrict__ WvlF,
                                                      const float* __restrict__ bqt,
                                                      const float* __restrict__ bk,
                                                      const float* __restrict__ bv,
                                                      short* __restrict__ QTh,
                                                      short* __restrict__ QTl,
                                                      short* __restrict__ Kh,
                                                      short* __restrict__ Kl,
                                                      short* __restrict__ VT) {
  const int id = blockIdx.x;
  const int region = id >> 9, tileG = id & 511;
  const int b = tileG >> 7, tileL = tileG & 127;
  const int tid = threadIdx.x, wave = tid >> 6, lane = tid & 63;
  const int l31 = lane & 31, half = lane >> 5;
  const short* BH;
  const short* BL;
  if (region == 0)      { BH = WqphF + (size_t)b * WFRAG; BL = WqplF + (size_t)b * WFRAG; }
  else if (region == 1) { BH = WkhF; BL = WklF; }
  else                  { BH = WvhF; BL = WvlF; }
  BH += (size_t)wave * 32768 + (size_t)lane * 8;
  BL += (size_t)wave * 32768 + (size_t)lane * 8;
  const short* AH = XAh + (size_t)tileG * XTILE + (size_t)lane * 8;
  const short* AL = XAl + (size_t)tileG * XTILE + (size_t)lane * 8;
  floatx16 accE, accO;
  #pragma unroll
  for (int r = 0; r < 16; ++r) { accE[r] = 0.f; accO[r] = 0.f; }
  for (int ks = 0; ks < 64; ks += 2) {
    short8 a0h = *(const short8*)(AH + (size_t)ks * 512);
    short8 a0l = *(const short8*)(AL + (size_t)ks * 512);
    short8 b0h = *(const short8*)(BH + (size_t)ks * 512);
    short8 b0l = *(const short8*)(BL + (size_t)ks * 512);
    short8 a1h = *(const short8*)(AH + (size_t)(ks + 1) * 512);
    short8 a1l = *(const short8*)(AL + (size_t)(ks + 1) * 512);
    short8 b1h = *(const short8*)(BH + (size_t)(ks + 1) * 512);
    short8 b1l = *(const short8*)(BL + (size_t)(ks + 1) * 512);
    accE = __builtin_amdgcn_mfma_f32_32x32x16_bf16(a0l, b0h, accE, 0, 0, 0);
    accO = __builtin_amdgcn_mfma_f32_32x32x16_bf16(a1l, b1h, accO, 0, 0, 0);
    accE = __builtin_amdgcn_mfma_f32_32x32x16_bf16(a0h, b0l, accE, 0, 0, 0);
    accO = __builtin_amdgcn_mfma_f32_32x32x16_bf16(a1h, b1l, accO, 0, 0, 0);
    accE = __builtin_amdgcn_mfma_f32_32x32x16_bf16(a0h, b0h, accE, 0, 0, 0);
    accO = __builtin_amdgcn_mfma_f32_32x32x16_bf16(a1h, b1h, accO, 0, 0, 0);
  }
  floatx16 acc;
  #pragma unroll
  for (int r = 0; r < 16; ++r) acc[r] = accE[r] + accO[r];
  // Epilogue. C/D: col(n) = wave*32 + l31, row(t) = (reg&3)+8*(reg>>2)+4*half.
  const int f = wave * 32 + l31;
  if (region <= 1) {
    short* Hp = (region == 0) ? QTh : Kh;
    short* Lp = (region == 0) ? QTl : Kl;
    const float bias = (region == 0) ? bqt[b * DKk + f] : bk[f];
    const int fks = f >> 4, fh = (f >> 3) & 1, fj = f & 7;
    const size_t qkbase =
        (size_t)b * BSTRIDE + (size_t)tileL * 4096 + (size_t)fks * 512 + fj;
    #pragma unroll
    for (int reg = 0; reg < 16; ++reg) {
      const int t = (reg & 3) + 8 * (reg >> 2) + 4 * half;
      const size_t off = qkbase + (size_t)(fh * 32 + t) * 8;
      float v = acc[reg] + bias;
      short hh = f2bf(v);
      Hp[off] = hh;
      Lp[off] = f2bf(v - bf2f(hh));
    }
  } else {
    // V -> 32x32x16 B-operand layout over [t][d]:
    // off(t,d) = ((d>>5)*256 + (t>>4))*512 + (((t>>3)&1)*32 + (d&31))*8 + (t&7)
    const float biasv = bv[f];
    #pragma unroll
    for (int g = 0; g < 4; ++g) {
      short4 s4;
      s4.x = f2bf(acc[4 * g + 0] + biasv);
      s4.y = f2bf(acc[4 * g + 1] + biasv);
      s4.z = f2bf(acc[4 * g + 2] + biasv);
      s4.w = f2bf(acc[4 * g + 3] + biasv);
      const size_t off = (size_t)b * BSTRIDE +
          (size_t)(wave * 256 + tileL * 2 + (g >> 1)) * 512 +
          (size_t)((g & 1) * 32 + l31) * 8 + 4 * half;
      *(short4*)&VT[off] = s4;
    }
  }
}

// ---------------- Kernel C1: m/l only. A=K, B=QT (transposed tiles). Software-
// pipelined: next tile's Kh prefetched into the alternate register buffer; current
// Kl loads hide behind the kh-only MFMA groups. Dual acc chains. -------------------
#define ML_TILE(CH)                                                              \
  {                                                                              \
    short8 cl[8];                                                                \
    _Pragma("unroll")                                                            \
    for (int ks = 0; ks < 8; ++ks)                                               \
      cl[ks] = *(const short8*)(Kl + kb + ks * 512);                             \
    floatx16 accA, accB;                                                         \
    _Pragma("unroll")                                                            \
    for (int r = 0; r < 16; ++r) { accA[r] = 0.f; accB[r] = 0.f; }               \
    _Pragma("unroll")                                                            \
    for (int ks = 0; ks < 4; ++ks) {                                             \
      accA = __builtin_amdgcn_mfma_f32_32x32x16_bf16(CH[ks], qh[ks], accA, 0, 0, 0);      \
      accB = __builtin_amdgcn_mfma_f32_32x32x16_bf16(CH[ks + 4], qh[ks + 4], accB, 0, 0, 0); \
    }                                                                            \
    _Pragma("unroll")                                                            \
    for (int ks = 0; ks < 4; ++ks) {                                             \
      accA = __builtin_amdgcn_mfma_f32_32x32x16_bf16(CH[ks], ql[ks], accA, 0, 0, 0);      \
      accB = __builtin_amdgcn_mfma_f32_32x32x16_bf16(CH[ks + 4], ql[ks + 4], accB, 0, 0, 0); \
    }                                                                            \
    _Pragma("unroll")                                                            \
    for (int ks = 0; ks < 4; ++ks) {                                             \
      accA = __builtin_amdgcn_mfma_f32_32x32x16_bf16(cl[ks], qh[ks], accA, 0, 0, 0);      \
      accB = __builtin_amdgcn_mfma_f32_32x32x16_bf16(cl[ks + 4], qh[ks + 4], accB, 0, 0, 0); \
    }                                                                            \
    float sv[16];                                                                \
    float tmax = -INFINITY;                                                      \
    _Pragma("unroll")                                                            \
    for (int r = 0; r < 16; ++r) {                                               \
      sv[r] = (accA[r] + accB[r]) * sc;                                          \
      tmax = fmaxf(tmax, sv[r]);                                                 \
    }                                                                            \
    const float mn = fmaxf(m, tmax);                                             \
    float ps = 0.f;                                                              \
    _Pragma("unroll")                                                            \
    for (int r = 0; r < 16; ++r) ps += __expf(sv[r] - mn);                       \
    l = l * __expf(m - mn) + ps;                                                 \
    m = mn;                                                                      \
  }

__global__ __launch_bounds__(256, 2) void ml_kernel(const short* __restrict__ QTh,
                                                    const short* __restrict__ QTl,
                                                    const short* __restrict__ Kh,
                                                    const short* __restrict__ Kl,
                                                    float* __restrict__ mrow,
                                                    float* __restrict__ linv) {
  __shared__ float smM[4][32], smL[4][32];
  const int id = blockIdx.x;
  const int xcd = id & 7;
  const int b = xcd >> 1;
  const int tile = ((id >> 3) << 1) + (xcd & 1);   // 0..127
  const int rowbase = tile * 32;
  const int tid = threadIdx.x;
  const int wave = tid >> 6, lane = tid & 63;
  const int l31 = lane & 31;
  const float sc = 0.088388347648318447f;  // 1/sqrt(128)
  const size_t qbase = (size_t)b * BSTRIDE + (size_t)tile * 4096 + lane * 8;
  short8 qh[8], ql[8];
  #pragma unroll
  for (int ks = 0; ks < 8; ++ks) {
    qh[ks] = *(const short8*)(QTh + qbase + ks * 512);
    ql[ks] = *(const short8*)(QTl + qbase + ks * 512);
  }
  const size_t kstep = 4 * 4096;
  size_t kb = (size_t)b * BSTRIDE + (size_t)wave * 4096 + (size_t)lane * 8;
  short8 hA[8], hB[8];
  #pragma unroll
  for (int ks = 0; ks < 8; ++ks) hA[ks] = *(const short8*)(Kh + kb + ks * 512);
  float m = -INFINITY, l = 0.f;
  for (int ii = 0; ii < 16; ++ii) {
    // sub-iteration 0: compute on hA, prefetch next Kh -> hB
    #pragma unroll
    for (int ks = 0; ks < 8; ++ks)
      hB[ks] = *(const short8*)(Kh + kb + kstep + ks * 512);
    ML_TILE(hA)
    kb += kstep;
    // sub-iteration 1: compute on hB, prefetch next Kh -> hA
    if (ii < 15) {
      #pragma unroll
      for (int ks = 0; ks < 8; ++ks)
        hA[ks] = *(const short8*)(Kh + kb + kstep + ks * 512);
    }
    ML_TILE(hB)
    kb += kstep;
  }
  {
    const float mo = __shfl_xor(m, 32, 64);
    const float lo = __shfl_xor(l, 32, 64);
    const float mn = fmaxf(m, mo);
    l = l * __expf(m - mn) + lo * __expf(mo - mn);
    m = mn;
  }
  if (lane < 32) { smM[wave][l31] = m; smL[wave][l31] = l; }
  __syncthreads();
  if (tid < 32) {
    float mm = smM[0][tid], ll = smL[0][tid];
    #pragma unroll
    for (int w = 1; w < 4; ++w) {
      const float mo = smM[w][tid], lo = smL[w][tid];
      const float mn = fmaxf(mm, mo);
      ll = ll * __expf(mm - mn) + lo * __expf(mo - mn);
      mm = mn;
    }
    mrow[b * SS + rowbase + tid] = mm;
    linv[b * SS + rowbase + tid] = 1.0f / ll;
  }
}

// ---------------- Kernel C2: recompute scores (pipelined), write p once (nt), P@V ---
#define PV_TILE(CH)                                                              \
  {                                                                              \
    short8 cl[8];                                                                \
    _Pragma("unroll")                                                            \
    for (int ks = 0; ks < 8; ++ks)                                               \
      cl[ks] = *(const short8*)(Kl + kb + ks * 512);                             \
    floatx16 acc;                                                                \
    _Pragma("unroll")                                                            \
    for (int r = 0; r < 16; ++r) acc[r] = 0.f;                                   \
    _Pragma("unroll")                                                            \
    for (int ks = 0; ks < 8; ++ks)                                               \
      acc = __builtin_amdgcn_mfma_f32_32x32x16_bf16(CH[ks], qh[ks], acc, 0, 0, 0);        \
    _Pragma("unroll")                                                            \
    for (int ks = 0; ks < 8; ++ks)                                               \
      acc = __builtin_amdgcn_mfma_f32_32x32x16_bf16(CH[ks], ql[ks], acc, 0, 0, 0);        \
    _Pragma("unroll")                                                            \
    for (int ks = 0; ks < 8; ++ks)                                               \
      acc = __builtin_amdgcn_mfma_f32_32x32x16_bf16(cl[ks], qh[ks], acc, 0, 0, 0);        \
    float p[16];                                                                 \
    _Pragma("unroll")                                                            \
    for (int r = 0; r < 16; ++r) p[r] = __expf(acc[r] * sc - m_i) * li;          \
    _Pragma("unroll")                                                            \
    for (int g = 0; g < 4; ++g) {                                                \
      floatx4 o = {p[4 * g], p[4 * g + 1], p[4 * g + 2], p[4 * g + 3]};          \
      __builtin_nontemporal_store(o, (floatx4*)(arow + ct * 32 + 8 * g));        \
    }                                                                            \
    short8 af0, af1;                                                             \
    _Pragma("unroll")                                                            \
    for (int rr = 0; rr < 4; ++rr) {                                             \
      const float shl = __shfl_xor(p[rr], 32, 64);                               \
      const float shh = __shfl_xor(p[rr + 4], 32, 64);                           \
      af0[rr] = f2bf(half ? shh : p[rr]);                                        \
      af0[rr + 4] = f2bf(half ? p[rr + 4] : shl);                                \
      const float shl2 = __shfl_xor(p[rr + 8], 32, 64);                          \
      const float shh2 = __shfl_xor(p[rr + 12], 32, 64);                         \
      af1[rr] = f2bf(half ? shh2 : p[rr + 8]);                                   \
      af1[rr + 4] = f2bf(half ? p[rr + 12] : shl2);                              \
    }                                                                            \
    _Pragma("unroll")                                                            \
    for (int dt = 0; dt < 4; ++dt) {                                             \
      short8 v0 = *(const short8*)(vtb + (size_t)(dt * 256 + ct * 2) * 512);     \
      pacc[dt] = __builtin_amdgcn_mfma_f32_32x32x16_bf16(af0, v0, pacc[dt], 0, 0, 0);     \
      short8 v1 = *(const short8*)(vtb + (size_t)(dt * 256 + ct * 2 + 1) * 512); \
      pacc[dt] = __builtin_amdgcn_mfma_f32_32x32x16_bf16(af1, v1, pacc[dt], 0, 0, 0);     \
    }                                                                            \
  }

__global__ __launch_bounds__(256, 2) void pv_kernel(const short* __restrict__ QTh,
                                                    const short* __restrict__ QTl,
                                                    const short* __restrict__ Kh,
                                                    const short* __restrict__ Kl,
                                                    const short* __restrict__ VT,
                                                    float* __restrict__ attn,
                                                    const float* __restrict__ mrow,
                                                    const float* __restrict__ linv,
                                                    float* __restrict__ outp) {
  __shared__ float sAcc[3][4][64][16];  // 48 KB partial-out exchange
  const int id = blockIdx.x;
  const int xcd = id & 7;
  const int b = xcd >> 1;
  const int tile = ((id >> 3) << 1) + (xcd & 1);   // 0..127
  const int rowbase = tile * 32;
  const int tid = threadIdx.x;
  const int wave = tid >> 6, lane = tid & 63;
  const int l31 = lane & 31, half = lane >> 5;
  const float sc = 0.088388347648318447f;
  const size_t qbase = (size_t)b * BSTRIDE + (size_t)tile * 4096 + lane * 8;
  short8 qh[8], ql[8];
  #pragma unroll
  for (int ks = 0; ks < 8; ++ks) {
    qh[ks] = *(const short8*)(QTh + qbase + ks * 512);
    ql[ks] = *(const short8*)(QTl + qbase + ks * 512);
  }
  const float m_i = mrow[b * SS + rowbase + l31];
  const float li = linv[b * SS + rowbase + l31];
  float* arow = attn + (size_t)b * SS * SS + (size_t)(rowbase + l31) * SS + 4 * half;
  const short* vtb = VT + (size_t)b * BSTRIDE + lane * 8;
  floatx16 pacc[4];
  #pragma unroll
  for (int dt = 0; dt < 4; ++dt)
    #pragma unroll
    for (int r = 0; r < 16; ++r) pacc[dt][r] = 0.f;
  const size_t kstep = 4 * 4096;
  size_t kb = (size_t)b * BSTRIDE + (size_t)wave * 4096 + (size_t)lane * 8;
  short8 hA[8], hB[8];
  #pragma unroll
  for (int ks = 0; ks < 8; ++ks) hA[ks] = *(const short8*)(Kh + kb + ks * 512);
  int ct = wave;
  for (int ii = 0; ii < 16; ++ii) {
    // sub-iteration 0: compute on hA, prefetch next Kh -> hB
    #pragma unroll
    for (int ks = 0; ks < 8; ++ks)
      hB[ks] = *(const short8*)(Kh + kb + kstep + ks * 512);
    PV_TILE(hA)
    kb += kstep;
    ct += 4;
    // sub-iteration 1: compute on hB, prefetch next Kh -> hA
    if (ii < 15) {
      #pragma unroll
      for (int ks = 0; ks < 8; ++ks)
        hA[ks] = *(const short8*)(Kh + kb + kstep + ks * 512);
    }
    PV_TILE(hB)
    kb += kstep;
    ct += 4;
  }
  if (wave > 0) {
    #pragma unroll
    for (int dt = 0; dt < 4; ++dt)
      #pragma unroll
      for (int r = 0; r < 16; ++r) sAcc[wave - 1][dt][lane][r] = pacc[dt][r];
  }
  __syncthreads();
  if (wave == 0) {
    #pragma unroll
    for (int dt = 0; dt < 4; ++dt)
      #pragma unroll
      for (int r = 0; r < 16; ++r) {
        const int q = (r & 3) + 8 * (r >> 2) + 4 * half;
        const float v = pacc[dt][r] + sAcc[0][dt][lane][r] + sAcc[1][dt][lane][r] +
                        sAcc[2][dt][lane][r];
        outp[((size_t)b * SS + rowbase + q) * DKk + dt * 32 + l31] = v;
      }
  }
}

extern "C" void kernel_launch(void* const* d_in, const int* in_sizes, int n_in,
                              void* d_out, int out_size, void* d_ws, size_t ws_size,
                              hipStream_t stream) {
  const float* x  = (const float*)d_in[0];
  const float* tp = (const float*)d_in[1];
  const float* Wq = (const float*)d_in[2];
  const float* bq = (const float*)d_in[3];
  const float* Wk = (const float*)d_in[4];
  const float* bk = (const float*)d_in[5];
  const float* Wv = (const float*)d_in[6];
  const float* bv = (const float*)d_in[7];
  const float* Wt = (const float*)d_in[8];
  const float* bt = (const float*)d_in[9];
  float* out  = (float*)d_out;
  float* attn = out + (size_t)BB * SS * DKk;
  float* ws = (float*)d_ws;
  float* Tws   = ws;                          // 65536
  float* bqt   = ws + 65536;                  // 512
  short* WqphF = (short*)(ws + 66048);        // 524288 shorts (4 batches)
  short* WqplF = (short*)(ws + 328192);
  short* WkhF  = (short*)(ws + 590336);       // 131072 shorts each
  short* WklF  = (short*)(ws + 655872);
  short* WvhF  = (short*)(ws + 721408);
  short* WvlF  = (short*)(ws + 786944);
  short* XAh   = (short*)(ws + 852480);       // 16777216 shorts
  short* XAl   = (short*)(ws + 9241088);
  short* QTh   = (short*)(ws + 17629696);     // 2097152 shorts each
  short* QTl   = (short*)(ws + 18678272);
  short* Kh    = (short*)(ws + 19726848);
  short* Kl    = (short*)(ws + 20775424);
  short* VT    = (short*)(ws + 21824000);
  float* mrow  = ws + 22872576;               // 16384
  float* lin   = ws + 22888960;               // 16384 -> end 22905344 fl = 91.6 MiB

  temb_kernel<<<dim3(8, 4), 256, 0, stream>>>(tp, Wt, bt, bq, Tws, bqt);
  wqp_kernel<<<dim3(1024, 4), 128, 0, stream>>>(Wq, Tws, WqphF, WqplF);
  wcast_kernel<<<dim3(64, 2), 256, 0, stream>>>(Wk, Wv, WkhF, WklF, WvhF, WvlF);
  xcast_kernel<<<512, 256, 0, stream>>>(x, XAh, XAl);
  proj_kernel<<<1536, 256, 0, stream>>>(XAh, XAl, WqphF, WqplF, WkhF, WklF,
                                        WvhF, WvlF, bqt, bk, bv,
                                        QTh, QTl, Kh, Kl, VT);
  ml_kernel<<<512, 256, 0, stream>>>(QTh, QTl, Kh, Kl, mrow, lin);
  pv_kernel<<<512, 256, 0, stream>>>(QTh, QTl, Kh, Kl, VT, attn, mrow, lin, out);
}